// Round 2
// baseline (258.702 us; speedup 1.0000x reference)
//
#include <hip/hip_runtime.h>
#include <math.h>

// ---------------------------------------------------------------------------
// Problem constants
// ---------------------------------------------------------------------------
#define B_    4
#define CIN_  64
#define COUT_ 32
#define MOD_  128
#define VOX_  32768       // 32^3
#define UPVOX_ 262144     // 64^3
#define TAPS_ 27
#define EPS_  1e-8f

#define HALO_   1224      // 6z * 6y * 34x halo voxels per 4z*4y*32x block
#define XUNITS_ 2448      // 2 halves-of-16ch * HALO_  (16-byte units per chunk)
#define CHUNK_HALVES_ 13824  // 16 cin * 27 taps * 32 oc

// Workspace layout (in floats)
#define WS_WF16  512      // f16 weights: 4b*4c*13824 halves
#define WS_Y     111104   // 4*32*32768 floats, conv output
#define WS_V32   4305408  // 4*32768 floats, vox head at 32^3

// Output layout (floats in d_out)
#define OUT_YUP  0
#define OUT_VOX  33554432

typedef _Float16 half8 __attribute__((ext_vector_type(8)));
typedef float floatx16 __attribute__((ext_vector_type(16)));
typedef float floatx4 __attribute__((ext_vector_type(4)));

// ---------------------------------------------------------------------------
// Kernel 1 (fused prep):
//   blockIdx.z < 4 : pack x (f32 NCDHW) -> xt (f16 [b][34][34][34][64], 0-pad)
//   blockIdx.z == 4: style GEMVs + softmax + bank mix + modulate + demodulate
//                    -> f16 weights (128 active blocks, one per (b,oc))
// ---------------------------------------------------------------------------
__global__ __launch_bounds__(256) void k_prep(
    const float* __restrict__ x,         // [4][64][32][32][32]
    const float* __restrict__ style,     // [4][128]
    const float* __restrict__ bank,      // [4][32][64][27]
    const float* __restrict__ affine_w,  // [64][128]
    const float* __restrict__ affine_b,  // [64]
    const float* __restrict__ sel_w,     // [4][128]
    const float* __restrict__ sel_b,     // [4]
    _Float16* __restrict__ xt,           // [4][34][34][34][64]
    _Float16* __restrict__ wf) {         // [b][c][t][h][oc][8]
  __shared__ float red[256];
  __shared__ float sS[64];
  __shared__ float sLg[4];
  __shared__ float sAl[4];
  const int tid = threadIdx.x;

  if (blockIdx.z == 4) {
    // ---------------- style + weights path ----------------
    const int sid = blockIdx.y * 34 + blockIdx.x;
    if (sid >= 128) return;
    const int b = sid >> 5;
    const int o = sid & 31;
    const float* st = style + b * MOD_;

    if (tid < 64) {
      float v = affine_b[tid];
      for (int k = 0; k < MOD_; ++k) v += st[k] * affine_w[tid * MOD_ + k];
      sS[tid] = v;
    } else if (tid < 68) {
      const int n = tid - 64;
      float l = sel_b[n];
      for (int k = 0; k < MOD_; ++k) l += st[k] * sel_w[n * MOD_ + k];
      sLg[n] = l;
    }
    __syncthreads();
    if (tid < 4) {
      const float m = fmaxf(fmaxf(sLg[0], sLg[1]), fmaxf(sLg[2], sLg[3]));
      float den = 0.f;
      for (int j = 0; j < 4; ++j) den += expf(sLg[j] - m);
      sAl[tid] = expf(sLg[tid] - m) / den;
    }
    __syncthreads();

    float al[4];
#pragma unroll
    for (int n = 0; n < 4; ++n) al[n] = sAl[n];

    float wv[7];
    float ss = 0.f;
#pragma unroll
    for (int r = 0; r < 7; ++r) {
      const int e = tid + r * 256;
      float v = 0.f;
      if (e < CIN_ * TAPS_) {
        const int i = e / TAPS_;
        const int t = e - i * TAPS_;
        const int base = (o * CIN_ + i) * TAPS_ + t;
        float bw = 0.f;
#pragma unroll
        for (int n = 0; n < 4; ++n)
          bw += al[n] * bank[base + n * (COUT_ * CIN_ * TAPS_)];
        v = bw * sS[i];
      }
      wv[r] = v;
      ss += v * v;
    }
    red[tid] = ss;
    __syncthreads();
    for (int stg = 128; stg > 0; stg >>= 1) {
      if (tid < stg) red[tid] += red[tid + stg];
      __syncthreads();
    }
    const float demod = rsqrtf(red[0] + EPS_);

#pragma unroll
    for (int r = 0; r < 7; ++r) {
      const int e = tid + r * 256;
      if (e < CIN_ * TAPS_) {
        const int i = e / TAPS_;
        const int t = e - i * TAPS_;
        const int c = i >> 4, h = (i >> 3) & 1, j = i & 7;
        wf[((((b * 4 + c) * TAPS_ + t) * 2 + h) * 32 + o) * 8 + j] =
            (_Float16)(wv[r] * demod);
      }
    }
    return;
  }

  // ---------------- pack path ----------------
  const int yp = blockIdx.x, zp = blockIdx.y, b = blockIdx.z;
  const int gz = zp - 1, gy = yp - 1;
  const bool zy_ok = ((unsigned)gz < 32u) && ((unsigned)gy < 32u);
  const int gzc = min(max(gz, 0), 31);
  const int gyc = min(max(gy, 0), 31);
  _Float16* dst = xt + (((size_t)(b * 34 + zp) * 34 + yp) * 34) * 64;
  const float* srow = x + ((size_t)b * CIN_) * VOX_ + gzc * 1024 + gyc * 32;
  for (int u = tid; u < 34 * 8; u += 256) {
    const int xp = u >> 3, q = u & 7;
    const int gx = xp - 1;
    const bool ok = zy_ok && ((unsigned)gx < 32u);
    const float m = ok ? 1.0f : 0.0f;
    const int gxc = min(max(gx, 0), 31);
    half8 h;
#pragma unroll
    for (int i = 0; i < 8; ++i) {
      const float v = srow[(size_t)(q * 8 + i) * VOX_ + gxc];
      h[i] = (_Float16)(v * m);
    }
    *(half8*)&dst[xp * 64 + q * 8] = h;
  }
}

// ---------------------------------------------------------------------------
// Kernel 2: implicit-GEMM conv, mfma_f32_32x32x16_f16.
// x-tiles double-buffered in LDS (78 KB); weights go L2 -> VGPR directly
// (each wave reads the whole 27.6 KB chunk slice anyway; wf is L2-resident,
// shared by the 64 blocks of a batch) -- this moves ~37% of the per-chunk
// LDS read traffic to the otherwise-idle VMEM pipe and deletes the wl
// staging writes. One barrier per chunk, software-pipelined x staging.
// Epilogue also computes v32 = vox_w . y (upsample commutes with 1x1 conv).
// ---------------------------------------------------------------------------
__global__ __launch_bounds__(256, 1) void k_conv(
    const _Float16* __restrict__ xt,   // [4][34][34][34][64]
    const _Float16* __restrict__ wf,   // [b][c][t][h][oc][8]
    const float* __restrict__ vox_w,   // [32]
    float* __restrict__ ws_y,          // [4][32][32768]
    float* __restrict__ v32) {         // [4][32768]
  __shared__ __align__(16) _Float16 xs[2][XUNITS_ * 8];     // 78336 B

  const int b  = blockIdx.y;
  const int bx = blockIdx.x;           // 64 blocks per batch
  const int z0 = (bx >> 3) * 4;
  const int y0 = (bx & 7) * 4;
  const int tid = threadIdx.x;
  const int w = tid >> 6;
  const int lane = tid & 63;
  const int hf = lane >> 5;
  const int col = lane & 31;
  const int wz = (w >> 1) * 2;         // wave z base in block (0/2)
  const int wy = (w & 1) * 2;          // wave y base in block (0/2)

  const _Float16* xtb = xt + (size_t)b * (34 * 34 * 34 * 64);
  const _Float16* wfb = wf + (size_t)b * 4 * CHUNK_HALVES_;
  // per-lane weight base: halves offset ((t*2+hf)*32+col)*8 = t*512 + (hf*32+col)*8
  const _Float16* wlane = wfb + ((size_t)(hf * 32 + col)) * 8;

  // Per-lane x-halo staging offsets (in halves) for units u = j*256 + tid
  int xoff[10];
  bool xok[10];
#pragma unroll
  for (int j = 0; j < 10; ++j) {
    const int u = j * 256 + tid;
    xok[j] = (u < XUNITS_);
    const int uc = xok[j] ? u : 0;
    const int h = uc / HALO_, hv = uc - h * HALO_;
    const int hz = hv / 204;
    const int rem = hv - hz * 204;
    const int hy = rem / 34;
    const int hx = rem - hy * 34;
    xoff[j] = (((z0 + hz) * 34 + (y0 + hy)) * 34 + hx) * 64 + h * 8;
  }

  floatx16 acc[2][2];
#pragma unroll
  for (int az = 0; az < 2; ++az)
#pragma unroll
    for (int ay = 0; ay < 2; ++ay)
#pragma unroll
      for (int r = 0; r < 16; ++r) acc[az][ay][r] = 0.f;

  half8 xv[10], afv[27];

  auto load_af = [&](int c) {
#pragma unroll
    for (int t = 0; t < TAPS_; ++t)
      afv[t] = *(const half8*)(wlane + (size_t)c * CHUNK_HALVES_ + t * 512);
  };
  auto load_chunk = [&](int c) {
#pragma unroll
    for (int j = 0; j < 10; ++j)
      xv[j] = *(const half8*)(xtb + xoff[j] + c * 16);
  };
  auto write_chunk = [&](int bufi) {
#pragma unroll
    for (int j = 0; j < 10; ++j) {
      const int u = j * 256 + tid;
      if (xok[j]) *(half8*)&xs[bufi][u * 8] = xv[j];
    }
  };
  auto compute = [&](int bufi) {
    const _Float16* xb_ = xs[bufi];
#pragma unroll
    for (int dx = 0; dx < 3; ++dx) {
      half8 Bf[4][4];
#pragma unroll
      for (int zs = 0; zs < 4; ++zs)
#pragma unroll
        for (int ys = 0; ys < 4; ++ys) {
          const int hv = ((wz + zs) * 6 + (wy + ys)) * 34 + dx + col;
          Bf[zs][ys] = *(const half8*)&xb_[(hf * HALO_ + hv) * 8];
        }
#pragma unroll
      for (int dz = 0; dz < 3; ++dz)
#pragma unroll
        for (int dy = 0; dy < 3; ++dy) {
          const half8 af = afv[(dz * 3 + dy) * 3 + dx];
          acc[0][0] = __builtin_amdgcn_mfma_f32_32x32x16_f16(af, Bf[dz][dy], acc[0][0], 0, 0, 0);
          acc[0][1] = __builtin_amdgcn_mfma_f32_32x32x16_f16(af, Bf[dz][dy + 1], acc[0][1], 0, 0, 0);
          acc[1][0] = __builtin_amdgcn_mfma_f32_32x32x16_f16(af, Bf[dz + 1][dy], acc[1][0], 0, 0, 0);
          acc[1][1] = __builtin_amdgcn_mfma_f32_32x32x16_f16(af, Bf[dz + 1][dy + 1], acc[1][1], 0, 0, 0);
        }
    }
  };

  // Pipeline: af(c) issued before xv(c+1), so the MFMA wait for af drains to
  // vmcnt(10) and leaves the x prefetch in flight. One barrier per chunk.
  load_af(0);
  load_chunk(0);
  write_chunk(0);
  __syncthreads();
  for (int c = 0; c < 4; ++c) {
    if (c < 3) load_chunk(c + 1);
    compute(c & 1);
    if (c < 3) {
      load_af(c + 1);
      write_chunk((c + 1) & 1);
      __syncthreads();
    }
  }

  // ---- epilogue: y stores + vox partial ----
  float vw[16];
#pragma unroll
  for (int r = 0; r < 16; ++r)
    vw[r] = vox_w[(r & 3) + 8 * (r >> 2) + 4 * hf];

  float* yb2 = ws_y + (size_t)b * COUT_ * VOX_;
#pragma unroll
  for (int az = 0; az < 2; ++az)
#pragma unroll
    for (int ay = 0; ay < 2; ++ay) {
      const int zz = z0 + wz + az, yy = y0 + wy + ay;
      const int vbase = zz * 1024 + yy * 32 + col;
      float p = 0.f;
#pragma unroll
      for (int r = 0; r < 16; ++r) {
        const int oc = (r & 3) + 8 * (r >> 2) + 4 * hf;
        yb2[(size_t)oc * VOX_ + vbase] = acc[az][ay][r];
        p = fmaf(vw[r], acc[az][ay][r], p);
      }
      p += __shfl_xor(p, 32);
      if (hf == 0) v32[((size_t)b << 15) + vbase] = p;
    }
}

// ---------------------------------------------------------------------------
// Kernel 3: trilinear 2x upsample. Each block now produces TWO z-pairs
// (4 output planes) from 4 staged source planes: read amplification on
// ws_y drops 3x -> 2x. Output stream (never re-read) uses non-temporal
// stores. Grid: (16 z-quads, 33 "channels" [32 y + v32], 4 b).
// ---------------------------------------------------------------------------
__global__ __launch_bounds__(256) void k_up(
    const float* __restrict__ ws_y,   // [4][32][32768]
    const float* __restrict__ v32,    // [4][32768]
    const float* __restrict__ vox_b,  // [1]
    float* __restrict__ out) {
  __shared__ float P[4][1056];        // 4 z-planes, row stride 33 (bank-safe)
  const int kq = blockIdx.x;          // z-quad 0..15 -> pairs 2kq, 2kq+1
  const int ch = blockIdx.y;          // 0..32 (32 == vox head)
  const int b = blockIdx.z;

  const float* src = (ch < 32) ? (ws_y + (((size_t)(b * 32 + ch)) << 15))
                               : (v32 + ((size_t)b << 15));
  for (int j = threadIdx.x; j < 1024; j += 256) {
    const int p = j >> 8, idx = j & 255;
    const int r = idx >> 3, q = (idx & 7) * 4;
    const int zsrc = min(max(2 * kq - 1 + p, 0), 31);
    const float4 v = *(const float4*)(src + (zsrc << 10) + r * 32 + q);
    float* dp = &P[p][r * 33 + q];
    dp[0] = v.x; dp[1] = v.y; dp[2] = v.z; dp[3] = v.w;
  }
  __syncthreads();

  const int yp = threadIdx.x >> 3;    // 0..31 (y-pair)
  const int xq = threadIdx.x & 7;     // 0..7  (8 out-x per thread)
  const int ym = max(yp - 1, 0) * 33, yc = yp * 33, ypp = min(yp + 1, 31) * 33;

  int gxi[6];
#pragma unroll
  for (int i = 0; i < 6; ++i) gxi[i] = min(max(4 * xq - 1 + i, 0), 31);

  const float vb = (ch == 32) ? vox_b[0] : 0.f;
  float* base0 = out + ((ch < 32) ? (OUT_YUP + (((size_t)(b * 32 + ch)) * UPVOX_))
                                  : (OUT_VOX + (size_t)b * UPVOX_)) +
                 (2 * yp) * 64 + 8 * xq;

#pragma unroll
  for (int zi = 0; zi < 2; ++zi) {    // source z-pair kz = 2kq + zi
    float ry[3][2][6];
#pragma unroll
    for (int p = 0; p < 3; ++p)       // local planes zi..zi+2 = kz-1,kz,kz+1
#pragma unroll
      for (int i = 0; i < 6; ++i) {
        const float a = P[zi + p][ym + gxi[i]];
        const float bb = P[zi + p][yc + gxi[i]];
        const float cc = P[zi + p][ypp + gxi[i]];
        ry[p][0][i] = fmaf(0.25f, a, 0.75f * bb);
        ry[p][1][i] = fmaf(0.25f, cc, 0.75f * bb);
      }

    float* base = base0 + (size_t)(2 * (2 * kq + zi)) * 4096;
#pragma unroll
    for (int zo = 0; zo < 2; ++zo)
#pragma unroll
      for (int yo = 0; yo < 2; ++yo) {
        float s[6];
#pragma unroll
        for (int i = 0; i < 6; ++i)
          s[i] = zo == 0 ? fmaf(0.25f, ry[0][yo][i], 0.75f * ry[1][yo][i])
                         : fmaf(0.25f, ry[2][yo][i], 0.75f * ry[1][yo][i]);
        float o[8];
#pragma unroll
        for (int ox = 0; ox < 8; ++ox) {
          const int k = ox >> 1;
          o[ox] = (ox & 1) ? fmaf(0.25f, s[k + 2], 0.75f * s[k + 1])
                           : fmaf(0.25f, s[k], 0.75f * s[k + 1]);
          o[ox] += vb;
        }
        float* dst = base + (size_t)zo * 4096 + yo * 64;
        floatx4 v0; v0.x = o[0]; v0.y = o[1]; v0.z = o[2]; v0.w = o[3];
        floatx4 v1; v1.x = o[4]; v1.y = o[5]; v1.z = o[6]; v1.w = o[7];
        __builtin_nontemporal_store(v0, (floatx4*)dst);
        __builtin_nontemporal_store(v1, (floatx4*)(dst + 4));
      }
  }
}

// ---------------------------------------------------------------------------
extern "C" void kernel_launch(void* const* d_in, const int* in_sizes, int n_in,
                              void* d_out, int out_size, void* d_ws, size_t ws_size,
                              hipStream_t stream) {
  const float* x        = (const float*)d_in[0];
  const float* style    = (const float*)d_in[1];
  const float* bank     = (const float*)d_in[2];
  const float* affine_w = (const float*)d_in[3];
  const float* affine_b = (const float*)d_in[4];
  const float* sel_w    = (const float*)d_in[5];
  const float* sel_b    = (const float*)d_in[6];
  const float* vox_w    = (const float*)d_in[7];
  const float* vox_b    = (const float*)d_in[8];
  float* out = (float*)d_out;
  float* ws  = (float*)d_ws;
  _Float16* wf16 = (_Float16*)(ws + WS_WF16);
  float* ws_y = ws + WS_Y;
  float* v32  = ws + WS_V32;
  // xt scratch lives at the front of d_out; k_up fully overwrites d_out.
  _Float16* xt = (_Float16*)d_out;

  k_prep<<<dim3(34, 34, 5), 256, 0, stream>>>(x, style, bank, affine_w, affine_b,
                                              sel_w, sel_b, xt, wf16);
  k_conv<<<dim3(64, B_), 256, 0, stream>>>(xt, wf16, vox_w, ws_y, v32);
  k_up<<<dim3(16, 33, B_), 256, 0, stream>>>(ws_y, v32, vox_b, out);
}

// Round 3
// 222.793 us; speedup vs baseline: 1.1612x; 1.1612x over previous
//
#include <hip/hip_runtime.h>
#include <math.h>

// ---------------------------------------------------------------------------
// Problem constants
// ---------------------------------------------------------------------------
#define B_    4
#define CIN_  64
#define COUT_ 32
#define MOD_  128
#define VOX_  32768       // 32^3
#define UPVOX_ 262144     // 64^3
#define TAPS_ 27
#define EPS_  1e-8f

// 2z*4y*32x output tile per block, halo 4z*6y*34x
#define HALO_   816       // 4 * 6 * 34
#define XUNITS_ 1632      // 2 halves-of-16ch * HALO_  (16-byte units per chunk)
#define CHUNK_HALVES_ 13824  // 16 cin * 27 taps * 32 oc

// Workspace layout (in floats)
#define WS_WF16  512      // f16 weights: 4b*4c*13824 halves
#define WS_Y     111104   // 4*32*32768 floats, conv output
#define WS_V32   4305408  // 4*32768 floats, vox head at 32^3

// Output layout (floats in d_out)
#define OUT_YUP  0
#define OUT_VOX  33554432

typedef _Float16 half8 __attribute__((ext_vector_type(8)));
typedef float floatx16 __attribute__((ext_vector_type(16)));

// ---------------------------------------------------------------------------
// Kernel 1 (fused prep):
//   blockIdx.z < 4 : pack x (f32 NCDHW) -> xt (f16 [b][34][34][34][64], 0-pad)
//   blockIdx.z == 4: style GEMVs + softmax + bank mix + modulate + demodulate
//                    -> f16 weights (128 active blocks, one per (b,oc))
// ---------------------------------------------------------------------------
__global__ __launch_bounds__(256) void k_prep(
    const float* __restrict__ x,         // [4][64][32][32][32]
    const float* __restrict__ style,     // [4][128]
    const float* __restrict__ bank,      // [4][32][64][27]
    const float* __restrict__ affine_w,  // [64][128]
    const float* __restrict__ affine_b,  // [64]
    const float* __restrict__ sel_w,     // [4][128]
    const float* __restrict__ sel_b,     // [4]
    _Float16* __restrict__ xt,           // [4][34][34][34][64]
    _Float16* __restrict__ wf) {         // [b][c][t][h][oc][8]
  __shared__ float red[256];
  __shared__ float sS[64];
  __shared__ float sLg[4];
  __shared__ float sAl[4];
  const int tid = threadIdx.x;

  if (blockIdx.z == 4) {
    // ---------------- style + weights path ----------------
    const int sid = blockIdx.y * 34 + blockIdx.x;
    if (sid >= 128) return;
    const int b = sid >> 5;
    const int o = sid & 31;
    const float* st = style + b * MOD_;

    if (tid < 64) {
      float v = affine_b[tid];
      for (int k = 0; k < MOD_; ++k) v += st[k] * affine_w[tid * MOD_ + k];
      sS[tid] = v;
    } else if (tid < 68) {
      const int n = tid - 64;
      float l = sel_b[n];
      for (int k = 0; k < MOD_; ++k) l += st[k] * sel_w[n * MOD_ + k];
      sLg[n] = l;
    }
    __syncthreads();
    if (tid < 4) {
      const float m = fmaxf(fmaxf(sLg[0], sLg[1]), fmaxf(sLg[2], sLg[3]));
      float den = 0.f;
      for (int j = 0; j < 4; ++j) den += expf(sLg[j] - m);
      sAl[tid] = expf(sLg[tid] - m) / den;
    }
    __syncthreads();

    float al[4];
#pragma unroll
    for (int n = 0; n < 4; ++n) al[n] = sAl[n];

    float wv[7];
    float ss = 0.f;
#pragma unroll
    for (int r = 0; r < 7; ++r) {
      const int e = tid + r * 256;
      float v = 0.f;
      if (e < CIN_ * TAPS_) {
        const int i = e / TAPS_;
        const int t = e - i * TAPS_;
        const int base = (o * CIN_ + i) * TAPS_ + t;
        float bw = 0.f;
#pragma unroll
        for (int n = 0; n < 4; ++n)
          bw += al[n] * bank[base + n * (COUT_ * CIN_ * TAPS_)];
        v = bw * sS[i];
      }
      wv[r] = v;
      ss += v * v;
    }
    red[tid] = ss;
    __syncthreads();
    for (int stg = 128; stg > 0; stg >>= 1) {
      if (tid < stg) red[tid] += red[tid + stg];
      __syncthreads();
    }
    const float demod = rsqrtf(red[0] + EPS_);

#pragma unroll
    for (int r = 0; r < 7; ++r) {
      const int e = tid + r * 256;
      if (e < CIN_ * TAPS_) {
        const int i = e / TAPS_;
        const int t = e - i * TAPS_;
        const int c = i >> 4, h = (i >> 3) & 1, j = i & 7;
        wf[((((b * 4 + c) * TAPS_ + t) * 2 + h) * 32 + o) * 8 + j] =
            (_Float16)(wv[r] * demod);
      }
    }
    return;
  }

  // ---------------- pack path ----------------
  const int yp = blockIdx.x, zp = blockIdx.y, b = blockIdx.z;
  const int gz = zp - 1, gy = yp - 1;
  const bool zy_ok = ((unsigned)gz < 32u) && ((unsigned)gy < 32u);
  const int gzc = min(max(gz, 0), 31);
  const int gyc = min(max(gy, 0), 31);
  _Float16* dst = xt + (((size_t)(b * 34 + zp) * 34 + yp) * 34) * 64;
  const float* srow = x + ((size_t)b * CIN_) * VOX_ + gzc * 1024 + gyc * 32;
  for (int u = tid; u < 34 * 8; u += 256) {
    const int xp = u >> 3, q = u & 7;
    const int gx = xp - 1;
    const bool ok = zy_ok && ((unsigned)gx < 32u);
    const float m = ok ? 1.0f : 0.0f;
    const int gxc = min(max(gx, 0), 31);
    half8 h;
#pragma unroll
    for (int i = 0; i < 8; ++i) {
      const float v = srow[(size_t)(q * 8 + i) * VOX_ + gxc];
      h[i] = (_Float16)(v * m);
    }
    *(half8*)&dst[xp * 64 + q * 8] = h;
  }
}

// ---------------------------------------------------------------------------
// Kernel 2: implicit-GEMM conv, mfma_f32_32x32x16_f16.
// 2z*4y*32x tile per block (512 blocks = 2/CU), x double-buffered in LDS
// (52 KB); weights L2 -> VGPR directly (no wl LDS). __launch_bounds__(256,2)
// caps VGPR at 256 so 2 blocks/CU (2 waves/SIMD) actually materializes:
// the second wave-set hides af L2 latency and ds_read latency.
// Epilogue also computes v32 = vox_w . y (upsample commutes with 1x1 conv).
// ---------------------------------------------------------------------------
__global__ __launch_bounds__(256, 2) void k_conv(
    const _Float16* __restrict__ xt,   // [4][34][34][34][64]
    const _Float16* __restrict__ wf,   // [b][c][t][h][oc][8]
    const float* __restrict__ vox_w,   // [32]
    float* __restrict__ ws_y,          // [4][32][32768]
    float* __restrict__ v32) {         // [4][32768]
  __shared__ __align__(16) _Float16 xs[2][XUNITS_ * 8];     // 52224 B

  const int b  = blockIdx.y;
  const int bx = blockIdx.x;           // 128 blocks per batch
  const int z0 = (bx >> 3) * 2;        // 16 z-tiles of 2
  const int y0 = (bx & 7) * 4;         // 8 y-tiles of 4
  const int tid = threadIdx.x;
  const int w = tid >> 6;
  const int lane = tid & 63;
  const int hf = lane >> 5;
  const int col = lane & 31;
  const int wz = w >> 1;               // wave z row in tile (0/1)
  const int wy = (w & 1) * 2;          // wave y base in tile (0/2)

  const _Float16* xtb = xt + (size_t)b * (34 * 34 * 34 * 64);
  const _Float16* wfb = wf + (size_t)b * 4 * CHUNK_HALVES_;
  // per-lane weight base: halves offset ((t*2+hf)*32+col)*8
  const _Float16* wlane = wfb + ((size_t)(hf * 32 + col)) * 8;

  // Per-lane x-halo staging offsets (in halves) for units u = j*256 + tid
  int xoff[7];
  bool xok[7];
#pragma unroll
  for (int j = 0; j < 7; ++j) {
    const int u = j * 256 + tid;
    xok[j] = (u < XUNITS_);
    const int uc = xok[j] ? u : 0;
    const int h = uc / HALO_, hv = uc - h * HALO_;
    const int hz = hv / 204;
    const int rem = hv - hz * 204;
    const int hy = rem / 34;
    const int hx = rem - hy * 34;
    xoff[j] = (((z0 + hz) * 34 + (y0 + hy)) * 34 + hx) * 64 + h * 8;
  }

  floatx16 acc[2];
#pragma unroll
  for (int ay = 0; ay < 2; ++ay)
#pragma unroll
    for (int r = 0; r < 16; ++r) acc[ay][r] = 0.f;

  half8 xv[7], afv[27];

  auto load_af = [&](int c) {
#pragma unroll
    for (int t = 0; t < TAPS_; ++t)
      afv[t] = *(const half8*)(wlane + (size_t)c * CHUNK_HALVES_ + t * 512);
  };
  auto load_chunk = [&](int c) {
#pragma unroll
    for (int j = 0; j < 7; ++j)
      xv[j] = *(const half8*)(xtb + xoff[j] + c * 16);
  };
  auto write_chunk = [&](int bufi) {
#pragma unroll
    for (int j = 0; j < 7; ++j) {
      const int u = j * 256 + tid;
      if (xok[j]) *(half8*)&xs[bufi][u * 8] = xv[j];
    }
  };
  auto compute = [&](int bufi) {
    const _Float16* xb_ = xs[bufi];
#pragma unroll
    for (int dx = 0; dx < 3; ++dx) {
      half8 Bf[3][4];
#pragma unroll
      for (int zs = 0; zs < 3; ++zs)
#pragma unroll
        for (int ys = 0; ys < 4; ++ys) {
          const int hv = ((wz + zs) * 6 + (wy + ys)) * 34 + dx + col;
          Bf[zs][ys] = *(const half8*)&xb_[(hf * HALO_ + hv) * 8];
        }
#pragma unroll
      for (int dz = 0; dz < 3; ++dz)
#pragma unroll
        for (int dy = 0; dy < 3; ++dy) {
          const half8 af = afv[(dz * 3 + dy) * 3 + dx];
          acc[0] = __builtin_amdgcn_mfma_f32_32x32x16_f16(af, Bf[dz][dy], acc[0], 0, 0, 0);
          acc[1] = __builtin_amdgcn_mfma_f32_32x32x16_f16(af, Bf[dz][dy + 1], acc[1], 0, 0, 0);
        }
    }
  };

  // Pipeline: afv(c) issued before the barrier of c-1, a full barrier ahead
  // of its use in compute(c). One barrier per chunk.
  load_af(0);
  load_chunk(0);
  write_chunk(0);
  __syncthreads();
  for (int c = 0; c < 4; ++c) {
    if (c < 3) load_chunk(c + 1);
    compute(c & 1);
    if (c < 3) {
      load_af(c + 1);
      write_chunk((c + 1) & 1);
      __syncthreads();
    }
  }

  // ---- epilogue: y stores + vox partial ----
  float vw[16];
#pragma unroll
  for (int r = 0; r < 16; ++r)
    vw[r] = vox_w[(r & 3) + 8 * (r >> 2) + 4 * hf];

  float* yb2 = ws_y + (size_t)b * COUT_ * VOX_;
#pragma unroll
  for (int ay = 0; ay < 2; ++ay) {
    const int zz = z0 + wz, yy = y0 + wy + ay;
    const int vbase = zz * 1024 + yy * 32 + col;
    float p = 0.f;
#pragma unroll
    for (int r = 0; r < 16; ++r) {
      const int oc = (r & 3) + 8 * (r >> 2) + 4 * hf;
      yb2[(size_t)oc * VOX_ + vbase] = acc[ay][r];
      p = fmaf(vw[r], acc[ay][r], p);
    }
    p += __shfl_xor(p, 32);
    if (hf == 0) v32[((size_t)b << 15) + vbase] = p;
  }
}

// ---------------------------------------------------------------------------
// Kernel 3: trilinear 2x upsample. Each block produces TWO z-pairs
// (4 output planes) from 4 staged source planes: read amplification on
// ws_y is 2x instead of 3x. Plain float4 stores (NT regressed r2).
// Grid: (16 z-quads, 33 "channels" [32 y + v32], 4 b).
// ---------------------------------------------------------------------------
__global__ __launch_bounds__(256) void k_up(
    const float* __restrict__ ws_y,   // [4][32][32768]
    const float* __restrict__ v32,    // [4][32768]
    const float* __restrict__ vox_b,  // [1]
    float* __restrict__ out) {
  __shared__ float P[4][1056];        // 4 z-planes, row stride 33 (bank-safe)
  const int kq = blockIdx.x;          // z-quad 0..15 -> pairs 2kq, 2kq+1
  const int ch = blockIdx.y;          // 0..32 (32 == vox head)
  const int b = blockIdx.z;

  const float* src = (ch < 32) ? (ws_y + (((size_t)(b * 32 + ch)) << 15))
                               : (v32 + ((size_t)b << 15));
  for (int j = threadIdx.x; j < 1024; j += 256) {
    const int p = j >> 8, idx = j & 255;
    const int r = idx >> 3, q = (idx & 7) * 4;
    const int zsrc = min(max(2 * kq - 1 + p, 0), 31);
    const float4 v = *(const float4*)(src + (zsrc << 10) + r * 32 + q);
    float* dp = &P[p][r * 33 + q];
    dp[0] = v.x; dp[1] = v.y; dp[2] = v.z; dp[3] = v.w;
  }
  __syncthreads();

  const int yp = threadIdx.x >> 3;    // 0..31 (y-pair)
  const int xq = threadIdx.x & 7;     // 0..7  (8 out-x per thread)
  const int ym = max(yp - 1, 0) * 33, yc = yp * 33, ypp = min(yp + 1, 31) * 33;

  int gxi[6];
#pragma unroll
  for (int i = 0; i < 6; ++i) gxi[i] = min(max(4 * xq - 1 + i, 0), 31);

  const float vb = (ch == 32) ? vox_b[0] : 0.f;
  float* base0 = out + ((ch < 32) ? (OUT_YUP + (((size_t)(b * 32 + ch)) * UPVOX_))
                                  : (OUT_VOX + (size_t)b * UPVOX_)) +
                 (2 * yp) * 64 + 8 * xq;

#pragma unroll
  for (int zi = 0; zi < 2; ++zi) {    // source z-pair kz = 2kq + zi
    float ry[3][2][6];
#pragma unroll
    for (int p = 0; p < 3; ++p)       // local planes zi..zi+2 = kz-1,kz,kz+1
#pragma unroll
      for (int i = 0; i < 6; ++i) {
        const float a = P[zi + p][ym + gxi[i]];
        const float bb = P[zi + p][yc + gxi[i]];
        const float cc = P[zi + p][ypp + gxi[i]];
        ry[p][0][i] = fmaf(0.25f, a, 0.75f * bb);
        ry[p][1][i] = fmaf(0.25f, cc, 0.75f * bb);
      }

    float* base = base0 + (size_t)(2 * (2 * kq + zi)) * 4096;
#pragma unroll
    for (int zo = 0; zo < 2; ++zo)
#pragma unroll
      for (int yo = 0; yo < 2; ++yo) {
        float s[6];
#pragma unroll
        for (int i = 0; i < 6; ++i)
          s[i] = zo == 0 ? fmaf(0.25f, ry[0][yo][i], 0.75f * ry[1][yo][i])
                         : fmaf(0.25f, ry[2][yo][i], 0.75f * ry[1][yo][i]);
        float o[8];
#pragma unroll
        for (int ox = 0; ox < 8; ++ox) {
          const int k = ox >> 1;
          o[ox] = (ox & 1) ? fmaf(0.25f, s[k + 2], 0.75f * s[k + 1])
                           : fmaf(0.25f, s[k], 0.75f * s[k + 1]);
          o[ox] += vb;
        }
        float4* dst = (float4*)(base + (size_t)zo * 4096 + yo * 64);
        float4 v0; v0.x = o[0]; v0.y = o[1]; v0.z = o[2]; v0.w = o[3];
        float4 v1; v1.x = o[4]; v1.y = o[5]; v1.z = o[6]; v1.w = o[7];
        dst[0] = v0;
        dst[1] = v1;
      }
  }
}

// ---------------------------------------------------------------------------
extern "C" void kernel_launch(void* const* d_in, const int* in_sizes, int n_in,
                              void* d_out, int out_size, void* d_ws, size_t ws_size,
                              hipStream_t stream) {
  const float* x        = (const float*)d_in[0];
  const float* style    = (const float*)d_in[1];
  const float* bank     = (const float*)d_in[2];
  const float* affine_w = (const float*)d_in[3];
  const float* affine_b = (const float*)d_in[4];
  const float* sel_w    = (const float*)d_in[5];
  const float* sel_b    = (const float*)d_in[6];
  const float* vox_w    = (const float*)d_in[7];
  const float* vox_b    = (const float*)d_in[8];
  float* out = (float*)d_out;
  float* ws  = (float*)d_ws;
  _Float16* wf16 = (_Float16*)(ws + WS_WF16);
  float* ws_y = ws + WS_Y;
  float* v32  = ws + WS_V32;
  // xt scratch lives at the front of d_out; k_up fully overwrites d_out.
  _Float16* xt = (_Float16*)d_out;

  k_prep<<<dim3(34, 34, 5), 256, 0, stream>>>(x, style, bank, affine_w, affine_b,
                                              sel_w, sel_b, xt, wf16);
  k_conv<<<dim3(128, B_), 256, 0, stream>>>(xt, wf16, vox_w, ws_y, v32);
  k_up<<<dim3(16, 33, B_), 256, 0, stream>>>(ws_y, v32, vox_b, out);
}

// Round 4
// 220.176 us; speedup vs baseline: 1.1750x; 1.0119x over previous
//
#include <hip/hip_runtime.h>
#include <math.h>

// ---------------------------------------------------------------------------
// Problem constants
// ---------------------------------------------------------------------------
#define B_    4
#define CIN_  64
#define COUT_ 32
#define MOD_  128
#define VOX_  32768       // 32^3
#define UPVOX_ 262144     // 64^3
#define TAPS_ 27
#define EPS_  1e-8f

// 2z*4y*32x output tile per block, halo 4z*6y*34x
#define HALO_   816       // 4 * 6 * 34
#define XUNITS_ 1632      // 2 halves-of-16ch * HALO_  (16-byte units per chunk)
#define CHUNK_HALVES_ 13824  // 16 cin * 27 taps * 32 oc

// Workspace layout (in floats)
#define WS_WF16  512      // f16 weights: 4b*4c*13824 halves
#define WS_Y     111104   // 4*32*32768 floats, conv output
#define WS_V32   4305408  // 4*32768 floats, vox head at 32^3

// Output layout (floats in d_out)
#define OUT_YUP  0
#define OUT_VOX  33554432

typedef _Float16 half8 __attribute__((ext_vector_type(8)));
typedef float floatx16 __attribute__((ext_vector_type(16)));

// ---------------------------------------------------------------------------
// Kernel 1 (fused prep):
//   blockIdx.z < 4 : pack x (f32 NCDHW) -> xt (f16 [b][34][34][34][64], 0-pad)
//   blockIdx.z == 4: style GEMVs + softmax + bank mix + modulate + demodulate
//                    -> f16 weights (128 active blocks, one per (b,oc))
// ---------------------------------------------------------------------------
__global__ __launch_bounds__(256) void k_prep(
    const float* __restrict__ x,         // [4][64][32][32][32]
    const float* __restrict__ style,     // [4][128]
    const float* __restrict__ bank,      // [4][32][64][27]
    const float* __restrict__ affine_w,  // [64][128]
    const float* __restrict__ affine_b,  // [64]
    const float* __restrict__ sel_w,     // [4][128]
    const float* __restrict__ sel_b,     // [4]
    _Float16* __restrict__ xt,           // [4][34][34][34][64]
    _Float16* __restrict__ wf) {         // [b][c][t][h][oc][8]
  __shared__ float red[256];
  __shared__ float sS[64];
  __shared__ float sLg[4];
  __shared__ float sAl[4];
  const int tid = threadIdx.x;

  if (blockIdx.z == 4) {
    // ---------------- style + weights path ----------------
    const int sid = blockIdx.y * 34 + blockIdx.x;
    if (sid >= 128) return;
    const int b = sid >> 5;
    const int o = sid & 31;
    const float* st = style + b * MOD_;

    if (tid < 64) {
      float v = affine_b[tid];
      for (int k = 0; k < MOD_; ++k) v += st[k] * affine_w[tid * MOD_ + k];
      sS[tid] = v;
    } else if (tid < 68) {
      const int n = tid - 64;
      float l = sel_b[n];
      for (int k = 0; k < MOD_; ++k) l += st[k] * sel_w[n * MOD_ + k];
      sLg[n] = l;
    }
    __syncthreads();
    if (tid < 4) {
      const float m = fmaxf(fmaxf(sLg[0], sLg[1]), fmaxf(sLg[2], sLg[3]));
      float den = 0.f;
      for (int j = 0; j < 4; ++j) den += expf(sLg[j] - m);
      sAl[tid] = expf(sLg[tid] - m) / den;
    }
    __syncthreads();

    float al[4];
#pragma unroll
    for (int n = 0; n < 4; ++n) al[n] = sAl[n];

    float wv[7];
    float ss = 0.f;
#pragma unroll
    for (int r = 0; r < 7; ++r) {
      const int e = tid + r * 256;
      float v = 0.f;
      if (e < CIN_ * TAPS_) {
        const int i = e / TAPS_;
        const int t = e - i * TAPS_;
        const int base = (o * CIN_ + i) * TAPS_ + t;
        float bw = 0.f;
#pragma unroll
        for (int n = 0; n < 4; ++n)
          bw += al[n] * bank[base + n * (COUT_ * CIN_ * TAPS_)];
        v = bw * sS[i];
      }
      wv[r] = v;
      ss += v * v;
    }
    red[tid] = ss;
    __syncthreads();
    for (int stg = 128; stg > 0; stg >>= 1) {
      if (tid < stg) red[tid] += red[tid + stg];
      __syncthreads();
    }
    const float demod = rsqrtf(red[0] + EPS_);

#pragma unroll
    for (int r = 0; r < 7; ++r) {
      const int e = tid + r * 256;
      if (e < CIN_ * TAPS_) {
        const int i = e / TAPS_;
        const int t = e - i * TAPS_;
        const int c = i >> 4, h = (i >> 3) & 1, j = i & 7;
        wf[((((b * 4 + c) * TAPS_ + t) * 2 + h) * 32 + o) * 8 + j] =
            (_Float16)(wv[r] * demod);
      }
    }
    return;
  }

  // ---------------- pack path ----------------
  const int yp = blockIdx.x, zp = blockIdx.y, b = blockIdx.z;
  const int gz = zp - 1, gy = yp - 1;
  const bool zy_ok = ((unsigned)gz < 32u) && ((unsigned)gy < 32u);
  const int gzc = min(max(gz, 0), 31);
  const int gyc = min(max(gy, 0), 31);
  _Float16* dst = xt + (((size_t)(b * 34 + zp) * 34 + yp) * 34) * 64;
  const float* srow = x + ((size_t)b * CIN_) * VOX_ + gzc * 1024 + gyc * 32;
  for (int u = tid; u < 34 * 8; u += 256) {
    const int xp = u >> 3, q = u & 7;
    const int gx = xp - 1;
    const bool ok = zy_ok && ((unsigned)gx < 32u);
    const float m = ok ? 1.0f : 0.0f;
    const int gxc = min(max(gx, 0), 31);
    half8 h;
#pragma unroll
    for (int i = 0; i < 8; ++i) {
      const float v = srow[(size_t)(q * 8 + i) * VOX_ + gxc];
      h[i] = (_Float16)(v * m);
    }
    *(half8*)&dst[xp * 64 + q * 8] = h;
  }
}

// ---------------------------------------------------------------------------
// Kernel 2: implicit-GEMM conv, mfma_f32_32x32x16_f16.
// 2z*4y*32x tile per block (512 blocks = 2/CU), x double-buffered in LDS
// (52 KB); weights L2 -> VGPR directly. __launch_bounds__(256,2) keeps
// 2 blocks/CU. NEW: bijective XCD swizzle of bx so each XCD owns a
// contiguous 2-z-tile slab per batch (~3.5 MB of xt incl halo fits the
// 4 MB per-XCD L2) -> halo re-reads become L2 hits instead of HBM refetch.
// Epilogue also computes v32 = vox_w . y (upsample commutes with 1x1 conv).
// ---------------------------------------------------------------------------
__global__ __launch_bounds__(256, 2) void k_conv(
    const _Float16* __restrict__ xt,   // [4][34][34][34][64]
    const _Float16* __restrict__ wf,   // [b][c][t][h][oc][8]
    const float* __restrict__ vox_w,   // [32]
    float* __restrict__ ws_y,          // [4][32][32768]
    float* __restrict__ v32) {         // [4][32768]
  __shared__ __align__(16) _Float16 xs[2][XUNITS_ * 8];     // 52224 B

  const int b  = blockIdx.y;
  // XCD swizzle: linear id mod 8 selects XCD; remap so XCD k gets bx in
  // [16k, 16k+16) = z-tiles {2k,2k+1} x all y. 128 % 8 == 0 -> bijective.
  const int bxr = blockIdx.x;          // 128 blocks per batch
  const int bx = ((bxr & 7) << 4) | (bxr >> 3);
  const int z0 = (bx >> 3) * 2;        // 16 z-tiles of 2
  const int y0 = (bx & 7) * 4;         // 8 y-tiles of 4
  const int tid = threadIdx.x;
  const int w = tid >> 6;
  const int lane = tid & 63;
  const int hf = lane >> 5;
  const int col = lane & 31;
  const int wz = w >> 1;               // wave z row in tile (0/1)
  const int wy = (w & 1) * 2;          // wave y base in tile (0/2)

  const _Float16* xtb = xt + (size_t)b * (34 * 34 * 34 * 64);
  const _Float16* wfb = wf + (size_t)b * 4 * CHUNK_HALVES_;
  // per-lane weight base: halves offset ((t*2+hf)*32+col)*8
  const _Float16* wlane = wfb + ((size_t)(hf * 32 + col)) * 8;

  // Per-lane x-halo staging offsets (in halves) for units u = j*256 + tid
  int xoff[7];
  bool xok[7];
#pragma unroll
  for (int j = 0; j < 7; ++j) {
    const int u = j * 256 + tid;
    xok[j] = (u < XUNITS_);
    const int uc = xok[j] ? u : 0;
    const int h = uc / HALO_, hv = uc - h * HALO_;
    const int hz = hv / 204;
    const int rem = hv - hz * 204;
    const int hy = rem / 34;
    const int hx = rem - hy * 34;
    xoff[j] = (((z0 + hz) * 34 + (y0 + hy)) * 34 + hx) * 64 + h * 8;
  }

  floatx16 acc[2];
#pragma unroll
  for (int ay = 0; ay < 2; ++ay)
#pragma unroll
    for (int r = 0; r < 16; ++r) acc[ay][r] = 0.f;

  half8 xv[7], afv[27];

  auto load_af = [&](int c) {
#pragma unroll
    for (int t = 0; t < TAPS_; ++t)
      afv[t] = *(const half8*)(wlane + (size_t)c * CHUNK_HALVES_ + t * 512);
  };
  auto load_chunk = [&](int c) {
#pragma unroll
    for (int j = 0; j < 7; ++j)
      xv[j] = *(const half8*)(xtb + xoff[j] + c * 16);
  };
  auto write_chunk = [&](int bufi) {
#pragma unroll
    for (int j = 0; j < 7; ++j) {
      const int u = j * 256 + tid;
      if (xok[j]) *(half8*)&xs[bufi][u * 8] = xv[j];
    }
  };
  auto compute = [&](int bufi) {
    const _Float16* xb_ = xs[bufi];
#pragma unroll
    for (int dx = 0; dx < 3; ++dx) {
      half8 Bf[3][4];
#pragma unroll
      for (int zs = 0; zs < 3; ++zs)
#pragma unroll
        for (int ys = 0; ys < 4; ++ys) {
          const int hv = ((wz + zs) * 6 + (wy + ys)) * 34 + dx + col;
          Bf[zs][ys] = *(const half8*)&xb_[(hf * HALO_ + hv) * 8];
        }
#pragma unroll
      for (int dz = 0; dz < 3; ++dz)
#pragma unroll
        for (int dy = 0; dy < 3; ++dy) {
          const half8 af = afv[(dz * 3 + dy) * 3 + dx];
          acc[0] = __builtin_amdgcn_mfma_f32_32x32x16_f16(af, Bf[dz][dy], acc[0], 0, 0, 0);
          acc[1] = __builtin_amdgcn_mfma_f32_32x32x16_f16(af, Bf[dz][dy + 1], acc[1], 0, 0, 0);
        }
    }
  };

  // Pipeline: afv(c) issued before the barrier of c-1, a full barrier ahead
  // of its use in compute(c). One barrier per chunk.
  load_af(0);
  load_chunk(0);
  write_chunk(0);
  __syncthreads();
  for (int c = 0; c < 4; ++c) {
    if (c < 3) load_chunk(c + 1);
    compute(c & 1);
    if (c < 3) {
      load_af(c + 1);
      write_chunk((c + 1) & 1);
      __syncthreads();
    }
  }

  // ---- epilogue: y stores + vox partial ----
  float vw[16];
#pragma unroll
  for (int r = 0; r < 16; ++r)
    vw[r] = vox_w[(r & 3) + 8 * (r >> 2) + 4 * hf];

  float* yb2 = ws_y + (size_t)b * COUT_ * VOX_;
#pragma unroll
  for (int ay = 0; ay < 2; ++ay) {
    const int zz = z0 + wz, yy = y0 + wy + ay;
    const int vbase = zz * 1024 + yy * 32 + col;
    float p = 0.f;
#pragma unroll
    for (int r = 0; r < 16; ++r) {
      const int oc = (r & 3) + 8 * (r >> 2) + 4 * hf;
      yb2[(size_t)oc * VOX_ + vbase] = acc[ay][r];
      p = fmaf(vw[r], acc[ay][r], p);
    }
    p += __shfl_xor(p, 32);
    if (hf == 0) v32[((size_t)b << 15) + vbase] = p;
  }
}

// ---------------------------------------------------------------------------
// Kernel 3: trilinear 2x upsample. Each block produces FOUR z-pairs
// (8 output planes) from 6 staged source planes: read amplification on
// ws_y drops 2x -> 1.5x. Grid (8, 33, 4): XCD = kq exactly, which with
// k_conv's swizzle means each XCD reads the ws_y z-slab its own L2 just
// wrote (planes 4k-1..4k+4 vs written 4k..4k+3) -> mostly L2-resident.
// ---------------------------------------------------------------------------
__global__ __launch_bounds__(256) void k_up(
    const float* __restrict__ ws_y,   // [4][32][32768]
    const float* __restrict__ v32,    // [4][32768]
    const float* __restrict__ vox_b,  // [1]
    float* __restrict__ out) {
  __shared__ float P[6][1056];        // 6 z-planes, row stride 33 (bank-safe)
  const int kq = blockIdx.x;          // z-quad 0..7 -> pairs 4kq..4kq+3
  const int ch = blockIdx.y;          // 0..32 (32 == vox head)
  const int b = blockIdx.z;

  const float* src = (ch < 32) ? (ws_y + (((size_t)(b * 32 + ch)) << 15))
                               : (v32 + ((size_t)b << 15));
  for (int j = threadIdx.x; j < 1536; j += 256) {
    const int p = j >> 8, idx = j & 255;
    const int r = idx >> 3, q = (idx & 7) * 4;
    const int zsrc = min(max(4 * kq - 1 + p, 0), 31);
    const float4 v = *(const float4*)(src + (zsrc << 10) + r * 32 + q);
    float* dp = &P[p][r * 33 + q];
    dp[0] = v.x; dp[1] = v.y; dp[2] = v.z; dp[3] = v.w;
  }
  __syncthreads();

  const int yp = threadIdx.x >> 3;    // 0..31 (y-pair)
  const int xq = threadIdx.x & 7;     // 0..7  (8 out-x per thread)
  const int ym = max(yp - 1, 0) * 33, yc = yp * 33, ypp = min(yp + 1, 31) * 33;

  int gxi[6];
#pragma unroll
  for (int i = 0; i < 6; ++i) gxi[i] = min(max(4 * xq - 1 + i, 0), 31);

  const float vb = (ch == 32) ? vox_b[0] : 0.f;
  float* base0 = out + ((ch < 32) ? (OUT_YUP + (((size_t)(b * 32 + ch)) * UPVOX_))
                                  : (OUT_VOX + (size_t)b * UPVOX_)) +
                 (2 * yp) * 64 + 8 * xq;

#pragma unroll
  for (int zi = 0; zi < 4; ++zi) {    // source z-pair kz = 4kq + zi
    float ry[3][2][6];
#pragma unroll
    for (int p = 0; p < 3; ++p)       // local planes zi..zi+2 = kz-1,kz,kz+1
#pragma unroll
      for (int i = 0; i < 6; ++i) {
        const float a = P[zi + p][ym + gxi[i]];
        const float bb = P[zi + p][yc + gxi[i]];
        const float cc = P[zi + p][ypp + gxi[i]];
        ry[p][0][i] = fmaf(0.25f, a, 0.75f * bb);
        ry[p][1][i] = fmaf(0.25f, cc, 0.75f * bb);
      }

    float* base = base0 + (size_t)(2 * (4 * kq + zi)) * 4096;
#pragma unroll
    for (int zo = 0; zo < 2; ++zo)
#pragma unroll
      for (int yo = 0; yo < 2; ++yo) {
        float s[6];
#pragma unroll
        for (int i = 0; i < 6; ++i)
          s[i] = zo == 0 ? fmaf(0.25f, ry[0][yo][i], 0.75f * ry[1][yo][i])
                         : fmaf(0.25f, ry[2][yo][i], 0.75f * ry[1][yo][i]);
        float o[8];
#pragma unroll
        for (int ox = 0; ox < 8; ++ox) {
          const int k = ox >> 1;
          o[ox] = (ox & 1) ? fmaf(0.25f, s[k + 2], 0.75f * s[k + 1])
                           : fmaf(0.25f, s[k], 0.75f * s[k + 1]);
          o[ox] += vb;
        }
        float4* dst = (float4*)(base + (size_t)zo * 4096 + yo * 64);
        float4 v0; v0.x = o[0]; v0.y = o[1]; v0.z = o[2]; v0.w = o[3];
        float4 v1; v1.x = o[4]; v1.y = o[5]; v1.z = o[6]; v1.w = o[7];
        dst[0] = v0;
        dst[1] = v1;
      }
  }
}

// ---------------------------------------------------------------------------
extern "C" void kernel_launch(void* const* d_in, const int* in_sizes, int n_in,
                              void* d_out, int out_size, void* d_ws, size_t ws_size,
                              hipStream_t stream) {
  const float* x        = (const float*)d_in[0];
  const float* style    = (const float*)d_in[1];
  const float* bank     = (const float*)d_in[2];
  const float* affine_w = (const float*)d_in[3];
  const float* affine_b = (const float*)d_in[4];
  const float* sel_w    = (const float*)d_in[5];
  const float* sel_b    = (const float*)d_in[6];
  const float* vox_w    = (const float*)d_in[7];
  const float* vox_b    = (const float*)d_in[8];
  float* out = (float*)d_out;
  float* ws  = (float*)d_ws;
  _Float16* wf16 = (_Float16*)(ws + WS_WF16);
  float* ws_y = ws + WS_Y;
  float* v32  = ws + WS_V32;
  // xt scratch lives at the front of d_out; k_up fully overwrites d_out.
  _Float16* xt = (_Float16*)d_out;

  k_prep<<<dim3(34, 34, 5), 256, 0, stream>>>(x, style, bank, affine_w, affine_b,
                                              sel_w, sel_b, xt, wf16);
  k_conv<<<dim3(128, B_), 256, 0, stream>>>(xt, wf16, vox_w, ws_y, v32);
  k_up<<<dim3(8, 33, B_), 256, 0, stream>>>(ws_y, v32, vox_b, out);
}